// Round 6
// baseline (30.407 us; speedup 1.0000x reference)
//
#include <hip/hip_runtime.h>
#include <math.h>

#define NC   80
#define BS   16
#define NOBJ 32

#define GRID     616          // multiple of 8; 616*256 threads grid-stride 158016 items
#define NSLOT    8
#define PER_SLOT (GRID / NSLOT)   // 77

// d_ws float-index layout:
//   [0, 616)         per-block partials (plain stores)
//   [640, 648)       slot sums (plain stores)
//   int idx 704+s*64 per-slot counters, one per 256B line   (zeroed each call)
//   int idx 1216     final counter                           (zeroed each call)
// memset region: bytes [2816, 2816+2052)

__device__ __forceinline__ float softplusf(float x) {
    return fmaxf(x, 0.0f) + log1pf(expf(-fabsf(x)));  // stable softplus
}

template<int H>
__device__ __forceinline__ float cell_quad(const float* __restrict__ p, int idx) {
    constexpr int HW = H * H;
    constexpr int Q  = HW / 4;          // float4s per plane
    int b = idx / Q;                    // compile-time divisor -> magic mul
    int r = idx - b * Q;
    const float4* pl = (const float4*)(p + (size_t)b * 144 * HW);
    float4 a0 = pl[r];
    float4 a1 = pl[r + Q];
    float4 a2 = pl[r + 2 * Q];
    float4 a3 = pl[r + 3 * Q];
    constexpr float inv = 1.0f / (float)(BS * HW);
    float sum = 0.0f, m, po;
    m = 0.25f * (a0.x + a1.x + a2.x + a3.x); po = 1.0f/(1.0f+expf(-m)); sum += po*po;
    m = 0.25f * (a0.y + a1.y + a2.y + a3.y); po = 1.0f/(1.0f+expf(-m)); sum += po*po;
    m = 0.25f * (a0.z + a1.z + a2.z + a3.z); po = 1.0f/(1.0f+expf(-m)); sum += po*po;
    m = 0.25f * (a0.w + a1.w + a2.w + a3.w); po = 1.0f/(1.0f+expf(-m)); sum += po*po;
    return (1.0f / 3.0f) * inv * sum;
}

__device__ __forceinline__ float block_reduce(float v, float* sdata) {
    #pragma unroll
    for (int off = 32; off > 0; off >>= 1)
        v += __shfl_down(v, off, 64);
    const int lane = threadIdx.x & 63;
    const int wid  = threadIdx.x >> 6;
    if (lane == 0) sdata[wid] = v;
    __syncthreads();
    return sdata[0] + sdata[1] + sdata[2] + sdata[3];   // valid in thread 0
}

__global__ void __launch_bounds__(256)
yolo_loss_main(const float* __restrict__ p0,
               const float* __restrict__ p1,
               const float* __restrict__ p2,
               const float* __restrict__ gtb,   // (16,32,4) f32
               const int*   __restrict__ gtc,   // (16,32) i32
               float* __restrict__ ws,          // scratch (counters pre-zeroed)
               float* __restrict__ out)
{
    constexpr int q0 = BS * 80 * 80 / 4;               // 25600
    constexpr int q1 = BS * 40 * 40 / 4;               // 6400
    constexpr int q2 = BS * 20 * 20 / 4;               // 1600
    constexpr int totalQuads = q0 + q1 + q2;           // 33600
    constexpr int nObjAll    = 3 * BS * NOBJ;          // 1536
    constexpr int totalLcls  = nObjAll * NC;           // 122880
    constexpr int total      = totalQuads + totalLcls + nObjAll;  // 158016

    float acc = 0.0f;

    for (int i = blockIdx.x * blockDim.x + threadIdx.x; i < total;
         i += GRID * 256) {
        if (i < totalQuads) {
            if (i < q0)           acc += cell_quad<80>(p0, i);
            else if (i < q0 + q1) acc += cell_quad<40>(p1, i - q0);
            else                  acc += cell_quad<20>(p2, i - q0 - q1);
        } else if (i < totalQuads + totalLcls) {
            // ---- lcls: one thread per (object, class channel) ----
            int t   = i - totalQuads;
            int oi  = t / NC;
            int c   = t - oi * NC;
            int s   = oi / (BS * NOBJ);
            int rem = oi - s * (BS * NOBJ);
            int b   = rem / NOBJ;
            int o   = rem - b * NOBJ;
            int w   = (s == 0) ? 80 : ((s == 1) ? 40 : 20);
            int hw  = w * w;
            const float* p = (s == 0) ? p0 : ((s == 1) ? p1 : p2);
            const float* g = gtb + ((size_t)b * NOBJ + o) * 4;
            int gx = min(max((int)(g[0] * w), 0), w - 1);
            int gy = min(max((int)(g[1] * w), 0), w - 1);
            const size_t cell = (size_t)b * 144 * hw + (size_t)gy * w + gx;
            float x = p[cell + (size_t)(64 + c) * hw];
            float lc = softplusf(x);
            if (c == gtc[b * NOBJ + o]) lc -= x;
            acc += (0.5f / 3.0f) * (1.0f / (float)NC) * lc;
        } else {
            // ---- per-object: lbox + lobj correction at marked cells ----
            int oi  = i - totalQuads - totalLcls;
            int s   = oi / (BS * NOBJ);
            int rem = oi - s * (BS * NOBJ);
            int b   = rem / NOBJ;
            int o   = rem - b * NOBJ;
            int w   = (s == 0) ? 80 : ((s == 1) ? 40 : 20);
            int hw  = w * w;
            const float* p = (s == 0) ? p0 : ((s == 1) ? p1 : p2);
            const float* g = gtb + ((size_t)b * NOBJ + o) * 4;
            float cx = g[0] * w, cy = g[1] * w, gw = g[2] * w, gh = g[3] * w;
            int gx = min(max((int)cx, 0), w - 1);
            int gy = min(max((int)cy, 0), w - 1);
            const size_t cell = (size_t)b * 144 * hw + (size_t)gy * w + gx;

            float bt0 = cx - (float)gx;
            float bt1 = cy - (float)gy;
            float bt2 = gw / (float)w;
            float bt3 = gh / (float)w;
            float c0 = p[cell];
            float c1 = p[cell + hw];
            float c2 = p[cell + 2 * (size_t)hw];
            float c3 = p[cell + 3 * (size_t)hw];
            float d0 = c0 - bt0, d1 = c1 - bt1, d2 = c2 - bt2, d3 = c3 - bt3;
            acc += (7.5f / 3.0f) * 0.25f * (d0*d0 + d1*d1 + d2*d2 + d3*d3);

            // lobj correction: only the FIRST object mapping to this cell
            bool first = true;
            for (int j = 0; j < o; ++j) {
                const float* gj = gtb + ((size_t)b * NOBJ + j) * 4;
                int gxj = min(max((int)(gj[0] * w), 0), w - 1);
                int gyj = min(max((int)(gj[1] * w), 0), w - 1);
                if (gxj == gx && gyj == gy) { first = false; break; }
            }
            if (first) {
                float m  = 0.25f * (c0 + c1 + c2 + c3);
                float po = 1.0f / (1.0f + expf(-m));
                float inv = 1.0f / (float)(BS * hw);
                acc += (1.0f / 3.0f) * (1.0f - 2.0f * po) * inv;  // (po-1)^2 - po^2
            }
        }
    }

    __shared__ float sdata[4];
    __shared__ int role;

    // ---- phase 1: block partial -> ws[blockIdx], release + slot counter ----
    float part = block_reduce(acc, sdata);
    const int slot = blockIdx.x & (NSLOT - 1);
    if (threadIdx.x == 0) {
        ws[blockIdx.x] = part;
        __threadfence();                               // release partial
        int old = atomicAdd((int*)ws + 704 + slot * 64, 1);
        role = (old == PER_SLOT - 1) ? 1 : 0;          // last block in slot
    }
    __syncthreads();
    if (!role) return;

    // ---- phase 2: slot finisher reduces its 77 partials ----
    __threadfence();                                   // acquire partials
    float v = (threadIdx.x < PER_SLOT) ? ws[slot + NSLOT * threadIdx.x] : 0.0f;
    __syncthreads();                                   // sdata reuse guard
    float ssum = block_reduce(v, sdata);
    if (threadIdx.x == 0) {
        ws[640 + slot] = ssum;
        __threadfence();                               // release slot sum
        int old2 = atomicAdd((int*)ws + 1216, 1);
        role = (old2 == NSLOT - 1) ? 1 : 0;            // last slot overall
    }
    __syncthreads();
    if (!role) return;

    // ---- phase 3: final finisher folds 8 slot sums, stores output ----
    if (threadIdx.x == 0) {
        __threadfence();                               // acquire slot sums
        float s = 0.0f;
        #pragma unroll
        for (int k = 0; k < NSLOT; ++k) s += ws[640 + k];
        out[0] = s;
    }
}

extern "C" void kernel_launch(void* const* d_in, const int* in_sizes, int n_in,
                              void* d_out, int out_size, void* d_ws, size_t ws_size,
                              hipStream_t stream) {
    const float* p0  = (const float*)d_in[0];
    const float* p1  = (const float*)d_in[1];
    const float* p2  = (const float*)d_in[2];
    const float* gtb = (const float*)d_in[3];
    const int*   gtc = (const int*)d_in[4];
    float* out = (float*)d_out;
    float* ws  = (float*)d_ws;

    // zero only the counter region (bytes 2816..4868) before the main kernel
    hipMemsetAsync((char*)d_ws + 2816, 0, 2052, stream);

    yolo_loss_main<<<GRID, 256, 0, stream>>>(p0, p1, p2, gtb, gtc, ws, out);
}

// Round 7
// 15.523 us; speedup vs baseline: 1.9589x; 1.9589x over previous
//
#include <hip/hip_runtime.h>
#include <math.h>

#define NC   80
#define BS   16
#define NOBJ 32

__device__ __forceinline__ float softplusf(float x) {
    // stable log(1+exp(x)) == max(x,0) + log1p(exp(-|x|))  (matches jax.nn.softplus)
    return fmaxf(x, 0.0f) + log1pf(expf(-fabsf(x)));
}

// 4 consecutive cells (one float4 per plane) of the lobj baseline, scale H
template<int H>
__device__ __forceinline__ float cell_quad(const float* __restrict__ p, int idx) {
    constexpr int HW = H * H;
    constexpr int Q  = HW / 4;          // float4s per plane
    int b = idx / Q;                    // compile-time divisor -> magic mul
    int r = idx - b * Q;
    const float4* pl = (const float4*)(p + (size_t)b * 144 * HW);
    float4 a0 = pl[r];
    float4 a1 = pl[r + Q];
    float4 a2 = pl[r + 2 * Q];
    float4 a3 = pl[r + 3 * Q];
    constexpr float inv = 1.0f / (float)(BS * HW);
    float sum = 0.0f, m, po;
    m = 0.25f * (a0.x + a1.x + a2.x + a3.x); po = 1.0f/(1.0f+expf(-m)); sum += po*po;
    m = 0.25f * (a0.y + a1.y + a2.y + a3.y); po = 1.0f/(1.0f+expf(-m)); sum += po*po;
    m = 0.25f * (a0.z + a1.z + a2.z + a3.z); po = 1.0f/(1.0f+expf(-m)); sum += po*po;
    m = 0.25f * (a0.w + a1.w + a2.w + a3.w); po = 1.0f/(1.0f+expf(-m)); sum += po*po;
    return (1.0f / 3.0f) * inv * sum;
}

__global__ void __launch_bounds__(256)
yolo_loss_main(const float* __restrict__ p0,
               const float* __restrict__ p1,
               const float* __restrict__ p2,
               const float* __restrict__ gtb,   // (16,32,4) f32
               const int*   __restrict__ gtc,   // (16,32) i32
               float* __restrict__ partials)
{
    constexpr int q0 = BS * 80 * 80 / 4;               // 25600
    constexpr int q1 = BS * 40 * 40 / 4;               // 6400
    constexpr int q2 = BS * 20 * 20 / 4;               // 1600
    constexpr int totalQuads = q0 + q1 + q2;           // 33600
    constexpr int nObjAll    = 3 * BS * NOBJ;          // 1536
    constexpr int totalLcls  = nObjAll * NC;           // 122880
    constexpr int total      = totalQuads + totalLcls + nObjAll;  // 158016

    float acc = 0.0f;

    for (int i = blockIdx.x * blockDim.x + threadIdx.x; i < total;
         i += gridDim.x * blockDim.x) {
        if (i < totalQuads) {
            if (i < q0)           acc += cell_quad<80>(p0, i);
            else if (i < q0 + q1) acc += cell_quad<40>(p1, i - q0);
            else                  acc += cell_quad<20>(p2, i - q0 - q1);
        } else if (i < totalQuads + totalLcls) {
            // ---- lcls: one thread per (object, class channel) ----
            int t   = i - totalQuads;
            int oi  = t / NC;                 // const divisors throughout
            int c   = t - oi * NC;
            int s   = oi / (BS * NOBJ);
            int rem = oi - s * (BS * NOBJ);
            int b   = rem / NOBJ;
            int o   = rem - b * NOBJ;
            int w   = (s == 0) ? 80 : ((s == 1) ? 40 : 20);
            int hw  = w * w;
            const float* p = (s == 0) ? p0 : ((s == 1) ? p1 : p2);
            const float* g = gtb + ((size_t)b * NOBJ + o) * 4;
            int gx = min(max((int)(g[0] * w), 0), w - 1);
            int gy = min(max((int)(g[1] * w), 0), w - 1);
            const size_t cell = (size_t)b * 144 * hw + (size_t)gy * w + gx;
            float x = p[cell + (size_t)(64 + c) * hw];
            float lc = softplusf(x);
            if (c == gtc[b * NOBJ + o]) lc -= x;
            acc += (0.5f / 3.0f) * (1.0f / (float)NC) * lc;
        } else {
            // ---- per-object: lbox + lobj correction at marked cells ----
            int oi  = i - totalQuads - totalLcls;
            int s   = oi / (BS * NOBJ);
            int rem = oi - s * (BS * NOBJ);
            int b   = rem / NOBJ;
            int o   = rem - b * NOBJ;
            int w   = (s == 0) ? 80 : ((s == 1) ? 40 : 20);
            int hw  = w * w;
            const float* p = (s == 0) ? p0 : ((s == 1) ? p1 : p2);
            const float* g = gtb + ((size_t)b * NOBJ + o) * 4;
            float cx = g[0] * w, cy = g[1] * w, gw = g[2] * w, gh = g[3] * w;
            int gx = min(max((int)cx, 0), w - 1);
            int gy = min(max((int)cy, 0), w - 1);
            const size_t cell = (size_t)b * 144 * hw + (size_t)gy * w + gx;

            float bt0 = cx - (float)gx;
            float bt1 = cy - (float)gy;
            float bt2 = gw / (float)w;
            float bt3 = gh / (float)w;
            float c0 = p[cell];
            float c1 = p[cell + hw];
            float c2 = p[cell + 2 * (size_t)hw];
            float c3 = p[cell + 3 * (size_t)hw];
            float d0 = c0 - bt0, d1 = c1 - bt1, d2 = c2 - bt2, d3 = c3 - bt3;
            acc += (7.5f / 3.0f) * 0.25f * (d0*d0 + d1*d1 + d2*d2 + d3*d3);

            // lobj correction: only the FIRST object mapping to this cell
            // (reference .set(1.0) scatter is idempotent across duplicates)
            bool first = true;
            for (int j = 0; j < o; ++j) {
                const float* gj = gtb + ((size_t)b * NOBJ + j) * 4;
                int gxj = min(max((int)(gj[0] * w), 0), w - 1);
                int gyj = min(max((int)(gj[1] * w), 0), w - 1);
                if (gxj == gx && gyj == gy) { first = false; break; }
            }
            if (first) {
                float m  = 0.25f * (c0 + c1 + c2 + c3);
                float po = 1.0f / (1.0f + expf(-m));
                float inv = 1.0f / (float)(BS * hw);
                acc += (1.0f / 3.0f) * (1.0f - 2.0f * po) * inv;  // (po-1)^2 - po^2
            }
        }
    }

    // ---- block reduction -> one partial per block (plain store, no zeroing) ----
    __shared__ float sdata[4];
    #pragma unroll
    for (int off = 32; off > 0; off >>= 1)
        acc += __shfl_down(acc, off, 64);
    const int lane = threadIdx.x & 63;
    const int wid  = threadIdx.x >> 6;
    if (lane == 0) sdata[wid] = acc;
    __syncthreads();
    if (threadIdx.x == 0)
        partials[blockIdx.x] = sdata[0] + sdata[1] + sdata[2] + sdata[3];
}

// single-wave finisher: no LDS, no barriers, 6 shuffles
__global__ void __launch_bounds__(64)
yolo_loss_reduce(const float* __restrict__ partials, int n, float* __restrict__ out)
{
    float acc = 0.0f;
    for (int i = threadIdx.x; i < n; i += 64) acc += partials[i];  // independent loads
    #pragma unroll
    for (int off = 32; off > 0; off >>= 1)
        acc += __shfl_down(acc, off, 64);
    if (threadIdx.x == 0) out[0] = acc;
}

extern "C" void kernel_launch(void* const* d_in, const int* in_sizes, int n_in,
                              void* d_out, int out_size, void* d_ws, size_t ws_size,
                              hipStream_t stream) {
    const float* p0  = (const float*)d_in[0];
    const float* p1  = (const float*)d_in[1];
    const float* p2  = (const float*)d_in[2];
    const float* gtb = (const float*)d_in[3];
    const int*   gtc = (const int*)d_in[4];
    float* out      = (float*)d_out;
    float* partials = (float*)d_ws;

    const int total = (BS * (80*80 + 40*40 + 20*20)) / 4   // cell quads
                    + 3 * BS * NOBJ * NC                   // lcls items
                    + 3 * BS * NOBJ;                       // box items
    const int block = 256;
    const int grid  = (total + block - 1) / block;         // 618

    yolo_loss_main<<<grid, block, 0, stream>>>(p0, p1, p2, gtb, gtc, partials);
    yolo_loss_reduce<<<1, 64, 0, stream>>>(partials, grid, out);
}

// Round 8
// 13.397 us; speedup vs baseline: 2.2697x; 1.1587x over previous
//
#include <hip/hip_runtime.h>
#include <math.h>

#define NC   80
#define BS   16
#define NOBJ 32

__device__ __forceinline__ float softplusf(float x) {
    // stable log(1+exp(x)) == max(x,0) + log1p(exp(-|x|))  (matches jax.nn.softplus)
    return fmaxf(x, 0.0f) + log1pf(expf(-fabsf(x)));
}

// 4 consecutive cells (one float4 per plane) of the lobj baseline, scale H
template<int H>
__device__ __forceinline__ float cell_quad(const float* __restrict__ p, int idx) {
    constexpr int HW = H * H;
    constexpr int Q  = HW / 4;          // float4s per plane
    int b = idx / Q;                    // compile-time divisor -> magic mul
    int r = idx - b * Q;
    const float4* pl = (const float4*)(p + (size_t)b * 144 * HW);
    float4 a0 = pl[r];
    float4 a1 = pl[r + Q];
    float4 a2 = pl[r + 2 * Q];
    float4 a3 = pl[r + 3 * Q];
    constexpr float inv = 1.0f / (float)(BS * HW);
    float sum = 0.0f, m, po;
    m = 0.25f * (a0.x + a1.x + a2.x + a3.x); po = 1.0f/(1.0f+expf(-m)); sum += po*po;
    m = 0.25f * (a0.y + a1.y + a2.y + a3.y); po = 1.0f/(1.0f+expf(-m)); sum += po*po;
    m = 0.25f * (a0.z + a1.z + a2.z + a3.z); po = 1.0f/(1.0f+expf(-m)); sum += po*po;
    m = 0.25f * (a0.w + a1.w + a2.w + a3.w); po = 1.0f/(1.0f+expf(-m)); sum += po*po;
    return (1.0f / 3.0f) * inv * sum;
}

__global__ void __launch_bounds__(256)
yolo_loss_main(const float* __restrict__ p0,
               const float* __restrict__ p1,
               const float* __restrict__ p2,
               const float* __restrict__ gtb,   // (16,32,4) f32
               const int*   __restrict__ gtc,   // (16,32) i32
               float* __restrict__ partials)
{
    constexpr int q0 = BS * 80 * 80 / 4;               // 25600
    constexpr int q1 = BS * 40 * 40 / 4;               // 6400
    constexpr int q2 = BS * 20 * 20 / 4;               // 1600
    constexpr int totalQuads = q0 + q1 + q2;           // 33600
    constexpr int nObjAll    = 3 * BS * NOBJ;          // 1536
    constexpr int totalLcls  = nObjAll * NC;           // 122880
    constexpr int total      = totalQuads + totalLcls + nObjAll;  // 158016

    float acc = 0.0f;

    for (int i = blockIdx.x * blockDim.x + threadIdx.x; i < total;
         i += gridDim.x * blockDim.x) {
        if (i < totalQuads) {
            if (i < q0)           acc += cell_quad<80>(p0, i);
            else if (i < q0 + q1) acc += cell_quad<40>(p1, i - q0);
            else                  acc += cell_quad<20>(p2, i - q0 - q1);
        } else if (i < totalQuads + totalLcls) {
            // ---- lcls: one thread per (object, class channel) ----
            int t   = i - totalQuads;
            int oi  = t / NC;                 // const divisors throughout
            int c   = t - oi * NC;
            int s   = oi / (BS * NOBJ);
            int rem = oi - s * (BS * NOBJ);
            int b   = rem / NOBJ;
            int o   = rem - b * NOBJ;
            int w   = (s == 0) ? 80 : ((s == 1) ? 40 : 20);
            int hw  = w * w;
            const float* p = (s == 0) ? p0 : ((s == 1) ? p1 : p2);
            const float* g = gtb + ((size_t)b * NOBJ + o) * 4;
            int gx = min(max((int)(g[0] * w), 0), w - 1);
            int gy = min(max((int)(g[1] * w), 0), w - 1);
            const size_t cell = (size_t)b * 144 * hw + (size_t)gy * w + gx;
            float x = p[cell + (size_t)(64 + c) * hw];
            float lc = softplusf(x);
            if (c == gtc[b * NOBJ + o]) lc -= x;
            acc += (0.5f / 3.0f) * (1.0f / (float)NC) * lc;
        } else {
            // ---- per-object: lbox + lobj correction at marked cells ----
            int oi  = i - totalQuads - totalLcls;
            int s   = oi / (BS * NOBJ);
            int rem = oi - s * (BS * NOBJ);
            int b   = rem / NOBJ;
            int o   = rem - b * NOBJ;
            int w   = (s == 0) ? 80 : ((s == 1) ? 40 : 20);
            int hw  = w * w;
            const float* p = (s == 0) ? p0 : ((s == 1) ? p1 : p2);
            const float* g = gtb + ((size_t)b * NOBJ + o) * 4;
            float cx = g[0] * w, cy = g[1] * w, gw = g[2] * w, gh = g[3] * w;
            int gx = min(max((int)cx, 0), w - 1);
            int gy = min(max((int)cy, 0), w - 1);
            const size_t cell = (size_t)b * 144 * hw + (size_t)gy * w + gx;

            float bt0 = cx - (float)gx;
            float bt1 = cy - (float)gy;
            float bt2 = gw / (float)w;
            float bt3 = gh / (float)w;
            float c0 = p[cell];
            float c1 = p[cell + hw];
            float c2 = p[cell + 2 * (size_t)hw];
            float c3 = p[cell + 3 * (size_t)hw];
            float d0 = c0 - bt0, d1 = c1 - bt1, d2 = c2 - bt2, d3 = c3 - bt3;
            acc += (7.5f / 3.0f) * 0.25f * (d0*d0 + d1*d1 + d2*d2 + d3*d3);

            // lobj correction: only the FIRST object mapping to this cell
            // (reference .set(1.0) scatter is idempotent across duplicates)
            bool first = true;
            for (int j = 0; j < o; ++j) {
                const float* gj = gtb + ((size_t)b * NOBJ + j) * 4;
                int gxj = min(max((int)(gj[0] * w), 0), w - 1);
                int gyj = min(max((int)(gj[1] * w), 0), w - 1);
                if (gxj == gx && gyj == gy) { first = false; break; }
            }
            if (first) {
                float m  = 0.25f * (c0 + c1 + c2 + c3);
                float po = 1.0f / (1.0f + expf(-m));
                float inv = 1.0f / (float)(BS * hw);
                acc += (1.0f / 3.0f) * (1.0f - 2.0f * po) * inv;  // (po-1)^2 - po^2
            }
        }
    }

    // ---- block reduction -> one partial per block (plain store, no zeroing) ----
    __shared__ float sdata[4];
    #pragma unroll
    for (int off = 32; off > 0; off >>= 1)
        acc += __shfl_down(acc, off, 64);
    const int lane = threadIdx.x & 63;
    const int wid  = threadIdx.x >> 6;
    if (lane == 0) sdata[wid] = acc;
    __syncthreads();
    if (threadIdx.x == 0)
        partials[blockIdx.x] = sdata[0] + sdata[1] + sdata[2] + sdata[3];
}

__global__ void __launch_bounds__(256)
yolo_loss_reduce(const float* __restrict__ partials, int n, float* __restrict__ out)
{
    float acc = 0.0f;
    for (int i = threadIdx.x; i < n; i += 256) acc += partials[i];
    __shared__ float sdata[4];
    #pragma unroll
    for (int off = 32; off > 0; off >>= 1)
        acc += __shfl_down(acc, off, 64);
    const int lane = threadIdx.x & 63;
    const int wid  = threadIdx.x >> 6;
    if (lane == 0) sdata[wid] = acc;
    __syncthreads();
    if (threadIdx.x == 0)
        out[0] = sdata[0] + sdata[1] + sdata[2] + sdata[3];
}

extern "C" void kernel_launch(void* const* d_in, const int* in_sizes, int n_in,
                              void* d_out, int out_size, void* d_ws, size_t ws_size,
                              hipStream_t stream) {
    const float* p0  = (const float*)d_in[0];
    const float* p1  = (const float*)d_in[1];
    const float* p2  = (const float*)d_in[2];
    const float* gtb = (const float*)d_in[3];
    const int*   gtc = (const int*)d_in[4];
    float* out      = (float*)d_out;
    float* partials = (float*)d_ws;

    const int total = (BS * (80*80 + 40*40 + 20*20)) / 4   // cell quads
                    + 3 * BS * NOBJ * NC                   // lcls items
                    + 3 * BS * NOBJ;                       // box items
    const int block = 256;
    const int grid  = (total + block - 1) / block;         // 618

    yolo_loss_main<<<grid, block, 0, stream>>>(p0, p1, p2, gtb, gtc, partials);
    yolo_loss_reduce<<<1, block, 0, stream>>>(partials, grid, out);
}